// Round 11
// baseline (704.816 us; speedup 1.0000x reference)
//
#include <hip/hip_runtime.h>
#include <hip/hip_bf16.h>

// Problem constants
#define B_  64
#define N_  16384
#define S_  64      // NUM_PATCHES
#define K_  32      // PATCH_POINTS
#define C1_ 64
#define C2_ 128
#define C3_ 384
#define R_  (B_*S_*K_)   // 131072 rows
#define BN_EPS_ 1e-5f

// ws layout (float offsets)
#define PATCH_OFF 0
#define CENT_OFF  (R_*3)                      // 393216
#define NB1_ 512
#define P1_OFF    (CENT_OFF + B_*S_*3)        // 405504 (mom: 48*9 floats)
#define SC1_OFF   (P1_OFF + NB1_*C1_*2)       // 471040
#define NB2_ 512
#define P2_OFF    (SC1_OFF + 2*C1_)           // 471168
#define SC2_OFF   (P2_OFF + NB2_*C2_*2)       // 602240
#define W2BF_OFF  (SC2_OFF + 2*C2_)           // 602496 (floats; holds 8192 shorts)
#define W3BF_OFF  (W2BF_OFF + 4096)           // 606592 (floats; holds 49152 shorts)
// end = 631168 floats (~2.52 MB)

#define MOMB_ 48   // moment-kernel blocks

typedef short bf16x8 __attribute__((ext_vector_type(8)));
typedef float f32x4  __attribute__((ext_vector_type(4)));

static __device__ __forceinline__ unsigned short f2bf(float f) {
  unsigned u = __float_as_uint(f);
  unsigned r = (u + 0x7fffu + ((u >> 16) & 1u)) >> 16;   // RNE
  return (unsigned short)r;
}

static __device__ __forceinline__ unsigned fToKey(float d) {
  unsigned u = __float_as_uint(d);
  return (u & 0x80000000u) ? ~u : (u | 0x80000000u);
}
static __device__ __forceinline__ float keyToF(unsigned k) {
  return (k & 0x80000000u) ? __uint_as_float(k & 0x7fffffffu)
                           : -__uint_as_float(~k);
}

// ---------------------------------------------------------------------------
// prep: convert W2 (128x64) and W3 (384x128) to bf16, row-major (plain).
// ---------------------------------------------------------------------------
__global__ void prep_kernel(const float* __restrict__ W2, const float* __restrict__ W3,
                            short* __restrict__ w2bf, short* __restrict__ w3bf) {
  int i = blockIdx.x * 256 + threadIdx.x;
  if (i < C2_*C1_) w2bf[i] = (short)f2bf(W2[i]);
  int j = i - C2_*C1_;
  if (j >= 0 && j < C3_*C2_) w3bf[j] = (short)f2bf(W3[j]);
}

// ---------------------------------------------------------------------------
// FPS: one block (1024 threads) per batch. 16 points/thread in registers.
// launch_bounds(1024,4): VGPR cap 128 -> no scratch spill. One barrier/step
// (double-buffered winner slots); final 16-winner reduce is lane-parallel.
// Distance replicates XLA contraction: fma(dz,dz,fma(dy,dy,dx*dx)).
// ---------------------------------------------------------------------------
__global__ __launch_bounds__(1024, 4) void fps_kernel(const float* __restrict__ x,
        float* __restrict__ centers, float* __restrict__ outCent) {
  int b = blockIdx.x;
  int t = threadIdx.x;
  const float* xb = x + (size_t)b * N_ * 3;
  float px[16], py[16], pz[16], dist[16];
#pragma unroll
  for (int j = 0; j < 16; ++j) {
    int n = j * 1024 + t;
    px[j] = xb[n*3+0]; py[j] = xb[n*3+1]; pz[j] = xb[n*3+2];
    dist[j] = 1e10f;
  }
  __shared__ float wd[2][16];
  __shared__ int   wi[2][16];
  float cx = xb[0], cy = xb[1], cz = xb[2];
  int lane = t & 63, wv = t >> 6;
  for (int s = 0; s < S_; ++s) {
    if (t == 0) {
      int task = b * S_ + s;
      centers[task*3+0] = cx; centers[task*3+1] = cy; centers[task*3+2] = cz;
      outCent[task*3+0] = cx; outCent[task*3+1] = cy; outCent[task*3+2] = cz;
    }
    float bd = -1.0f; int bn = 0;
#pragma unroll
    for (int j = 0; j < 16; ++j) {
      float dx = px[j]-cx, dy = py[j]-cy, dz = pz[j]-cz;
      float d = __builtin_fmaf(dz, dz, __builtin_fmaf(dy, dy, dx*dx));
      float dm = fminf(dist[j], d);
      dist[j] = dm;
      int n = j*1024 + t;
      if (dm > bd) { bd = dm; bn = n; }
    }
#pragma unroll
    for (int m = 1; m < 64; m <<= 1) {
      float od = __shfl_xor(bd, m, 64); int on = __shfl_xor(bn, m, 64);
      if (od > bd || (od == bd && on < bn)) { bd = od; bn = on; }
    }
    int buf = s & 1;
    if (lane == 0) { wd[buf][wv] = bd; wi[buf][wv] = bn; }
    __syncthreads();
    float vd = wd[buf][lane & 15];
    int   vi = wi[buf][lane & 15];
#pragma unroll
    for (int m = 1; m < 16; m <<= 1) {
      float od = __shfl_xor(vd, m, 64); int oi = __shfl_xor(vi, m, 64);
      if (od > vd || (od == vd && oi < vi)) { vd = od; vi = oi; }
    }
    int gn = vi;
    cx = xb[gn*3+0]; cy = xb[gn*3+1]; cz = xb[gn*3+2];
  }
}

// ---------------------------------------------------------------------------
// query_ball v7: 512 threads (8 waves), key[32]/thread, no spill.
// 1-barrier pass-indexed counts; sampled T0 (256 samples, E[count]=64);
// linear secant (no transcendentals) into window [32,96]; wave0-only rank
// of <=96 candidates -> exact reference top-32 by (key, idx). Fallback =
// exact radix bisection with 1-barrier counts + index-ordered tie fill.
// ---------------------------------------------------------------------------
__global__ __launch_bounds__(512, 4) void qb_kernel(const float* __restrict__ x,
        const float* __restrict__ centers, float* __restrict__ patches) {
  int t = threadIdx.x;
  int lane = t & 63, wv = t >> 6;    // 8 waves
  int task = blockIdx.x;
  int b = task >> 6;
  const float* xb = x + (size_t)b * N_ * 3;
  float cx = centers[task*3+0], cy = centers[task*3+1], cz = centers[task*3+2];
  float A = __builtin_fmaf(cz, cz, __builtin_fmaf(cy, cy, cx*cx));

  __shared__ unsigned wcnt[44][8];      // pass-indexed count slots (no reuse)
  __shared__ unsigned wredA[8], wredB[8];
  __shared__ int cwv[8];
  __shared__ unsigned long long cand[96];
  __shared__ int winIdx[32];
  __shared__ int sortedIdx[32];

  unsigned key[32];
  unsigned kmin = 0xffffffffu, ksam = 0xffffffffu;
#pragma unroll
  for (int j = 0; j < 32; ++j) {
    int n = j * 512 + t;
    float qx = xb[n*3+0], qy = xb[n*3+1], qz = xb[n*3+2];
    float Bn = __builtin_fmaf(qz, qz, __builtin_fmaf(qy, qy, qx*qx));
    float dt = __builtin_fmaf(cz, qz, __builtin_fmaf(cy, qy, cx*qx));
    float d  = __builtin_fmaf(-2.0f, dt, A + Bn);
    unsigned k = fToKey(d);
    key[j] = k;
    kmin = min(kmin, k);
  }
  if ((lane & 1) == 0) ksam = key[0];     // 256 samples/block
#pragma unroll
  for (int m = 1; m < 64; m <<= 1) {
    kmin = min(kmin, (unsigned)__shfl_xor((int)kmin, m, 64));
    ksam = min(ksam, (unsigned)__shfl_xor((int)ksam, m, 64));
  }
  if (lane == 0) { wredA[wv] = kmin; wredB[wv] = ksam; }
  __syncthreads();
  unsigned gmin = wredA[0], T0 = wredB[0];
#pragma unroll
  for (int w = 1; w < 8; ++w) { gmin = min(gmin, wredA[w]); T0 = min(T0, wredB[w]); }

  int pc = 0;
  // 1-barrier exact block count (pass-indexed slot, uniform result)
  auto countLess = [&](unsigned T) -> int {
    int cc = 0;
#pragma unroll
    for (int j = 0; j < 32; ++j) cc += (key[j] < T) ? 1 : 0;
#pragma unroll
    for (int m = 1; m < 64; m <<= 1) cc += __shfl_xor(cc, m, 64);
    if (lane == 0) wcnt[pc][wv] = (unsigned)cc;
    __syncthreads();
    int tot = 0;
#pragma unroll
    for (int w = 0; w < 8; ++w) tot += (int)wcnt[pc][w];
    ++pc;
    return tot;
  };

  unsigned Tcur = T0;
  int c = countLess(Tcur);
  float dmin = keyToF(gmin);
  for (int iter = 0; iter < 4 && !(c >= 32 && c <= 96); ++iter) {
    float dcur = keyToF(Tcur);
    if (!(dcur > dmin)) break;
    float cf = fmaxf((float)c, 1.0f);
    float dnew = dmin + (dcur - dmin) * (64.0f / cf);   // linear secant
    unsigned Tn = fToKey(dnew);
    if (Tn == Tcur) break;
    Tcur = Tn;
    c = countLess(Tcur);
  }

  // ballot-compact {key < T} into cand[] (per-wave prefix bases; 2 barriers)
  auto compactLess = [&](unsigned T) -> int {
    int wc = 0;
#pragma unroll
    for (int j = 0; j < 32; ++j)
      wc += (int)__popcll(__ballot(key[j] < T));
    __syncthreads();
    if (lane == 0) cwv[wv] = wc;
    __syncthreads();
    int base = 0;
    for (int w = 0; w < wv; ++w) base += cwv[w];
    int tot = 0;
#pragma unroll
    for (int w = 0; w < 8; ++w) tot += cwv[w];
    int p2 = base;
#pragma unroll
    for (int j = 0; j < 32; ++j) {
      bool p = key[j] < T;
      unsigned long long mk = __ballot(p);
      if (p) {
        int pos = p2 + (int)__popcll(mk & ((1ull << lane) - 1ull));
        cand[pos] = ((unsigned long long)key[j] << 32) | (unsigned)(j*512 + t);
      }
      p2 += (int)__popcll(mk);
    }
    return tot;
  };

  int ctot;
  if (c >= 32 && c <= 96) {
    ctot = compactLess(Tcur);
  } else {
    // fallback: exact boundary key via radix bisection (AND/OR bit-skip)
    unsigned a = 0xffffffffu, o = 0u;
#pragma unroll
    for (int j = 0; j < 32; ++j) { a &= key[j]; o |= key[j]; }
#pragma unroll
    for (int m = 1; m < 64; m <<= 1) {
      a &= (unsigned)__shfl_xor((int)a, m, 64);
      o |= (unsigned)__shfl_xor((int)o, m, 64);
    }
    __syncthreads();
    if (lane == 0) { wredA[wv] = a; wredB[wv] = o; }
    __syncthreads();
    unsigned gA = wredA[0], gO = wredB[0];
#pragma unroll
    for (int w = 1; w < 8; ++w) { gA &= wredA[w]; gO |= wredB[w]; }
    unsigned diff = gA ^ gO;
    unsigned result = 0u;
    for (int bit = 31; bit >= 0; --bit) {
      unsigned msk = 1u << bit;
      if (!(diff & msk)) { result |= (gA & msk); continue; }
      if (countLess(result | msk) < 32) result |= msk;
    }
    unsigned Tx = result;                 // exact 32nd-key boundary
    int cl = compactLess(Tx);             // strict-less, < 32
    int need = 32 - cl;
    int picked = -1;
    for (int r = 0; r < need; ++r) {
      int candn = 0x7fffffff;
#pragma unroll
      for (int j = 0; j < 32; ++j) {
        int n = j*512 + t;
        if (key[j] == Tx && n > picked && n < candn) candn = n;
      }
#pragma unroll
      for (int m = 1; m < 64; m <<= 1) candn = min(candn, __shfl_xor(candn, m, 64));
      __syncthreads();
      if (lane == 0) wredA[wv] = (unsigned)candn;
      __syncthreads();
      unsigned wmin = wredA[0];
#pragma unroll
      for (int w = 1; w < 8; ++w) wmin = min(wmin, wredA[w]);
      int winner = (int)wmin;
      if (t == 0) cand[cl + r] = ((unsigned long long)Tx << 32) | (unsigned)winner;
      picked = winner;
    }
    ctot = 32;
  }
  __syncthreads();

  // wave0-only rank: 2 candidates/lane, <=96 broadcast reads once
  if (wv == 0) {
    unsigned long long c0 = (lane < ctot) ? cand[lane] : ~0ull;
    unsigned long long c1 = (lane + 64 < ctot) ? cand[lane + 64] : ~0ull;
    int r0 = 0, r1 = 0;
    for (int jj = 0; jj < ctot; ++jj) {
      unsigned long long ov = cand[jj];
      r0 += (ov < c0) ? 1 : 0;
      r1 += (ov < c1) ? 1 : 0;
    }
    if (lane < ctot && r0 < 32) winIdx[r0] = (int)(c0 & 0xffffffffu);
    if (lane + 64 < ctot && r1 < 32) winIdx[r1] = (int)(c1 & 0xffffffffu);
  }
  __syncthreads();
  if (t < 32) {
    int v = winIdx[t];
    int slot = 0;
#pragma unroll
    for (int j = 0; j < 32; ++j) slot += (winIdx[j] < v) ? 1 : 0;
    sortedIdx[slot] = v;
  }
  __syncthreads();
  if (t < 32) {
    int n = sortedIdx[t];
    float qx = xb[n*3+0], qy = xb[n*3+1], qz = xb[n*3+2];
    size_t row = (size_t)task * K_ + t;
    patches[row*3+0] = qx - cx;
    patches[row*3+1] = qy - cy;
    patches[row*3+2] = qz - cz;
  }
}

// ---------------------------------------------------------------------------
// mom: 9 moments of patches (Sx,Sy,Sz,Sxx,Syy,Szz,Sxy,Sxz,Syz) -> mom[48][9]
// ---------------------------------------------------------------------------
__global__ __launch_bounds__(256) void mom_kernel(const float* __restrict__ patches,
        float* __restrict__ mom) {
  int t = threadIdx.x;
  float s[9] = {0,0,0,0,0,0,0,0,0};
  for (int r = blockIdx.x*256 + t; r < R_; r += MOMB_*256) {
    const float* p = patches + (size_t)r*3;
    float x0 = p[0], y0 = p[1], z0 = p[2];
    s[0] += x0; s[1] += y0; s[2] += z0;
    s[3] += x0*x0; s[4] += y0*y0; s[5] += z0*z0;
    s[6] += x0*y0; s[7] += x0*z0; s[8] += y0*z0;
  }
  __shared__ float red[4][9];
  int lane = t & 63, wv = t >> 6;
#pragma unroll
  for (int k = 0; k < 9; ++k) {
    float v = s[k];
#pragma unroll
    for (int m = 1; m < 64; m <<= 1) v += __shfl_xor(v, m, 64);
    if (lane == 0) red[wv][k] = v;
  }
  __syncthreads();
  if (t < 9) mom[blockIdx.x*9 + t] = red[0][t] + red[1][t] + red[2][t] + red[3][t];
}

// ---------------------------------------------------------------------------
// finalize1: layer-1 BN scale/shift from the 9 moments (double combine).
// ---------------------------------------------------------------------------
__global__ void finalize1_kernel(const float* __restrict__ mom,
        const float* __restrict__ W1, const float* __restrict__ b1,
        const float* __restrict__ g, const float* __restrict__ be,
        float* __restrict__ scale, float* __restrict__ shift) {
  int o = threadIdx.x;
  __shared__ double M[9];
  if (o < 9) {
    double ss = 0.0;
    for (int i = 0; i < MOMB_; ++i) ss += (double)mom[i*9 + o];
    M[o] = ss;
  }
  __syncthreads();
  if (o >= C1_) return;
  double w0 = W1[o*3], w1 = W1[o*3+1], w2 = W1[o*3+2], bb = b1[o];
  double wSp = w0*M[0] + w1*M[1] + w2*M[2];
  double s1 = wSp + (double)R_*bb;
  double s2 = w0*w0*M[3] + w1*w1*M[4] + w2*w2*M[5]
            + 2.0*(w0*w1*M[6] + w0*w2*M[7] + w1*w2*M[8])
            + 2.0*bb*wSp + (double)R_*bb*bb;
  float m   = (float)(s1 / (double)R_);
  float eh2 = (float)(s2 / (double)R_);
  float v = eh2 - m*m;
  float rs = rsqrtf(v + BN_EPS_);
  float sc = g[o] * rs;
  scale[o] = sc;
  shift[o] = be[o] - m*sc;
}

// ---------------------------------------------------------------------------
// finalize: deterministic sum of partials -> scale/shift (BN affine form).
// If bias != nullptr, folds a pre-BN linear bias into shift.
// ---------------------------------------------------------------------------
__global__ void finalize_kernel(const float* __restrict__ part, int nblk, int nch,
        const float* __restrict__ g, const float* __restrict__ be,
        const float* __restrict__ bias,
        float* __restrict__ scale, float* __restrict__ shift) {
  int o = threadIdx.x;
  if (o >= nch) return;
  double s1 = 0.0, s2 = 0.0;
  for (int i = 0; i < nblk; ++i) {
    s1 += (double)part[i*nch*2 + o*2 + 0];
    s2 += (double)part[i*nch*2 + o*2 + 1];
  }
  float m   = (float)(s1 / (double)R_);
  float eh2 = (float)(s2 / (double)R_);
  float v = eh2 - m*m;
  float rs = rsqrtf(v + BN_EPS_);
  float sc = g[o] * rs;
  scale[o] = sc;
  float sh = be[o] - m*sc;
  if (bias) sh += bias[o]*sc;
  shift[o] = sh;
}

// ---------------------------------------------------------------------------
// stats2: 512 blocks x 256 rows (2 tiles of 128): recompute a1 tile (LDS),
// h2 = a1@W2^T + b2 (fp32), per-channel sum/sumsq.
// ---------------------------------------------------------------------------
__global__ __launch_bounds__(256) void stats2_kernel(const float* __restrict__ patches,
        const float* __restrict__ W1, const float* __restrict__ b1,
        const float* __restrict__ sc1, const float* __restrict__ sh1,
        const float* __restrict__ W2, const float* __restrict__ b2,
        float* __restrict__ part) {
  __shared__ float a1L[128][68];
  __shared__ float red[2][128][2];
  int t = threadIdx.x;
  float4 wreg[16];
  const float4* w2r = (const float4*)(W2 + (t & 127)*64);
#pragma unroll
  for (int c = 0; c < 16; ++c) wreg[c] = w2r[c];
  float bb = b2[t & 127];
  float s1 = 0.f, s2 = 0.f;
  int rg = t >> 7;
  for (int tile = 0; tile < 2; ++tile) {
    int r0 = blockIdx.x * 256 + tile * 128;
    {
      int r = t & 127, oh = t >> 7;
      const float* p = patches + (size_t)(r0 + r) * 3;
      float p0 = p[0], p1 = p[1], p2 = p[2];
#pragma unroll
      for (int j = 0; j < 32; ++j) {
        int o = oh*32 + j;
        float h = p0*W1[o*3] + p1*W1[o*3+1] + p2*W1[o*3+2] + b1[o];
        a1L[r][o] = fmaxf(h*sc1[o] + sh1[o], 0.f);
      }
    }
    __syncthreads();
    for (int i = 0; i < 64; ++i) {
      int r = rg*64 + i;
      float acc = bb;
      const float4* a4 = (const float4*)(&a1L[r][0]);
#pragma unroll
      for (int c = 0; c < 16; ++c) {
        float4 a = a4[c];
        acc += a.x*wreg[c].x; acc += a.y*wreg[c].y;
        acc += a.z*wreg[c].z; acc += a.w*wreg[c].w;
      }
      s1 += acc; s2 += acc*acc;
    }
    __syncthreads();
  }
  red[rg][t & 127][0] = s1; red[rg][t & 127][1] = s2;
  __syncthreads();
  if (t < 128) {
    part[blockIdx.x*256 + t*2 + 0] = red[0][t][0] + red[1][t][0];
    part[blockIdx.x*256 + t*2 + 1] = red[0][t][1] + red[1][t][1];
  }
}

// ---------------------------------------------------------------------------
// embed (MFMA): 4 tasks/block (M=128 rows), 256 threads (4 waves, 1 task/wave).
// ---------------------------------------------------------------------------
__global__ __launch_bounds__(256) void embed_kernel(
        const float* __restrict__ patches,
        const float* __restrict__ W1, const float* __restrict__ b1,
        const float* __restrict__ sc1, const float* __restrict__ sh1,
        const short* __restrict__ w2bf, const float* __restrict__ sc2,
        const float* __restrict__ sh2f,
        const short* __restrict__ w3bf, const float* __restrict__ b3,
        float* __restrict__ out) {
  __shared__ char lds[49152];   // a1L @0 (16KB), a2L @16384 (32KB)
  int t = threadIdx.x;
  int l = t & 63, w = t >> 6;
  int lo = l & 15, hi = l >> 4;

  // ---- P1 ----
  {
    int row = t >> 1, half = t & 1;
    const float* p = patches + ((size_t)blockIdx.x*128 + row)*3;
    float p0 = p[0], p1 = p[1], p2 = p[2];
    int swz = (row & 7) << 4;
    char* dst = lds + row*128;
#pragma unroll
    for (int g = 0; g < 4; ++g) {
      unsigned short pk[8];
#pragma unroll
      for (int j = 0; j < 8; ++j) {
        int o = half*32 + g*8 + j;
        float h = p0*W1[o*3] + p1*W1[o*3+1] + p2*W1[o*3+2] + b1[o];
        pk[j] = f2bf(fmaxf(h*sc1[o] + sh1[o], 0.f));
      }
      int4 v;
      v.x = pk[0] | (pk[1]<<16); v.y = pk[2] | (pk[3]<<16);
      v.z = pk[4] | (pk[5]<<16); v.w = pk[6] | (pk[7]<<16);
      *(int4*)(dst + (((half*64 + g*16)) ^ swz)) = v;
    }
  }
  __syncthreads();

  // ---- P2 ----
  {
    bf16x8 af[2][2];
#pragma unroll
    for (int mt = 0; mt < 2; ++mt) {
      int row = w*32 + mt*16 + lo;
#pragma unroll
      for (int ks = 0; ks < 2; ++ks)
        af[mt][ks] = *(const bf16x8*)(lds + row*128 + ((ks*64 + hi*16) ^ ((row&7)<<4)));
    }
#pragma unroll
    for (int nt = 0; nt < 8; ++nt) {
      f32x4 acc0 = {0.f,0.f,0.f,0.f}, acc1 = {0.f,0.f,0.f,0.f};
      int n = nt*16 + lo;
#pragma unroll
      for (int ks = 0; ks < 2; ++ks) {
        bf16x8 bfv = *(const bf16x8*)(w2bf + n*64 + ks*32 + hi*8);
        acc0 = __builtin_amdgcn_mfma_f32_16x16x32_bf16(af[0][ks], bfv, acc0, 0, 0, 0);
        acc1 = __builtin_amdgcn_mfma_f32_16x16x32_bf16(af[1][ks], bfv, acc1, 0, 0, 0);
      }
      float sc = sc2[n], sh = sh2f[n];
#pragma unroll
      for (int mt = 0; mt < 2; ++mt) {
        f32x4 c = mt ? acc1 : acc0;
#pragma unroll
        for (int r = 0; r < 4; ++r) {
          int row = w*32 + mt*16 + hi*4 + r;
          unsigned short v = f2bf(fmaxf(c[r]*sc + sh, 0.f));
          *(short*)(lds + 16384 + row*256 + ((n*2) ^ ((row&7)<<4))) = (short)v;
        }
      }
    }
  }
  __syncthreads();

  // ---- P3 ----
  {
    bf16x8 af[2][4];
#pragma unroll
    for (int mt = 0; mt < 2; ++mt) {
      int row = w*32 + mt*16 + lo;
#pragma unroll
      for (int ks = 0; ks < 4; ++ks)
        af[mt][ks] = *(const bf16x8*)(lds + 16384 + row*256 + ((ks*64 + hi*16) ^ ((row&7)<<4)));
    }
    size_t gtask = (size_t)blockIdx.x*4 + w;
#pragma unroll 4
    for (int nt = 0; nt < 24; ++nt) {
      f32x4 acc0 = {0.f,0.f,0.f,0.f}, acc1 = {0.f,0.f,0.f,0.f};
      int e = nt*16 + lo;
#pragma unroll
      for (int ks = 0; ks < 4; ++ks) {
        bf16x8 bfv = *(const bf16x8*)(w3bf + e*128 + ks*32 + hi*8);
        acc0 = __builtin_amdgcn_mfma_f32_16x16x32_bf16(af[0][ks], bfv, acc0, 0, 0, 0);
        acc1 = __builtin_amdgcn_mfma_f32_16x16x32_bf16(af[1][ks], bfv, acc1, 0, 0, 0);
      }
      float m0 = fmaxf(fmaxf(acc0[0], acc0[1]), fmaxf(acc0[2], acc0[3]));
      float m1 = fmaxf(fmaxf(acc1[0], acc1[1]), fmaxf(acc1[2], acc1[3]));
      float m = fmaxf(m0, m1);
      m = fmaxf(m, __shfl_xor(m, 16, 64));
      m = fmaxf(m, __shfl_xor(m, 32, 64));
      if (l < 16) out[gtask*C3_ + e] = m + b3[e];
    }
  }
}

// ---------------------------------------------------------------------------
extern "C" void kernel_launch(void* const* d_in, const int* in_sizes, int n_in,
                              void* d_out, int out_size, void* d_ws, size_t ws_size,
                              hipStream_t stream) {
  (void)in_sizes; (void)n_in; (void)out_size; (void)ws_size;
  const float* x   = (const float*)d_in[0];
  const float* W1  = (const float*)d_in[1];
  const float* b1  = (const float*)d_in[2];
  const float* g1  = (const float*)d_in[3];
  const float* be1 = (const float*)d_in[4];
  const float* W2  = (const float*)d_in[5];
  const float* b2  = (const float*)d_in[6];
  const float* g2  = (const float*)d_in[7];
  const float* be2 = (const float*)d_in[8];
  const float* W3  = (const float*)d_in[9];
  const float* b3  = (const float*)d_in[10];
  float* out = (float*)d_out;
  float* ws  = (float*)d_ws;

  float* patches = ws + PATCH_OFF;
  float* centers = ws + CENT_OFF;
  float* mom1    = ws + P1_OFF;
  float* sc1     = ws + SC1_OFF; float* sh1 = sc1 + C1_;
  float* part2   = ws + P2_OFF;
  float* sc2     = ws + SC2_OFF; float* sh2 = sc2 + C2_;
  short* w2bf    = (short*)(ws + W2BF_OFF);
  short* w3bf    = (short*)(ws + W3BF_OFF);
  float* outCent = out + (size_t)B_*S_*C3_;

  prep_kernel<<<dim3((C2_*C1_ + C3_*C2_)/256), dim3(256), 0, stream>>>(W2, W3, w2bf, w3bf);
  fps_kernel<<<dim3(B_), dim3(1024), 0, stream>>>(x, centers, outCent);
  qb_kernel<<<dim3(4096), dim3(512), 0, stream>>>(x, centers, patches);
  mom_kernel<<<dim3(MOMB_), dim3(256), 0, stream>>>(patches, mom1);
  finalize1_kernel<<<dim3(1), dim3(64), 0, stream>>>(mom1, W1, b1, g1, be1, sc1, sh1);
  stats2_kernel<<<dim3(NB2_), dim3(256), 0, stream>>>(patches, W1, b1, sc1, sh1, W2, b2, part2);
  finalize_kernel<<<dim3(1), dim3(128), 0, stream>>>(part2, NB2_, C2_, g2, be2, b2, sc2, sh2);
  embed_kernel<<<dim3(1024), dim3(256), 0, stream>>>(patches, W1, b1, sc1, sh1,
                                                     w2bf, sc2, sh2, w3bf, b3, out);
}

// Round 12
// 666.918 us; speedup vs baseline: 1.0568x; 1.0568x over previous
//
#include <hip/hip_runtime.h>
#include <hip/hip_bf16.h>

// Problem constants
#define B_  64
#define N_  16384
#define S_  64      // NUM_PATCHES
#define K_  32      // PATCH_POINTS
#define C1_ 64
#define C2_ 128
#define C3_ 384
#define R_  (B_*S_*K_)   // 131072 rows
#define BN_EPS_ 1e-5f

// ws layout (float offsets)
#define PATCH_OFF 0
#define CENT_OFF  (R_*3)                      // 393216
#define NB1_ 512
#define P1_OFF    (CENT_OFF + B_*S_*3)        // 405504 (mom: 48*9 floats)
#define SC1_OFF   (P1_OFF + NB1_*C1_*2)       // 471040
#define NB2_ 512
#define P2_OFF    (SC1_OFF + 2*C1_)           // 471168
#define SC2_OFF   (P2_OFF + NB2_*C2_*2)       // 602240
#define W2BF_OFF  (SC2_OFF + 2*C2_)           // 602496 (floats; holds 8192 shorts)
#define W3BF_OFF  (W2BF_OFF + 4096)           // 606592 (floats; holds 49152 shorts)
// end = 631168 floats (~2.52 MB)

#define MOMB_ 48   // moment-kernel blocks

typedef short bf16x8 __attribute__((ext_vector_type(8)));
typedef float f32x4  __attribute__((ext_vector_type(4)));

static __device__ __forceinline__ unsigned short f2bf(float f) {
  unsigned u = __float_as_uint(f);
  unsigned r = (u + 0x7fffu + ((u >> 16) & 1u)) >> 16;   // RNE
  return (unsigned short)r;
}

static __device__ __forceinline__ unsigned fToKey(float d) {
  unsigned u = __float_as_uint(d);
  return (u & 0x80000000u) ? ~u : (u | 0x80000000u);
}
static __device__ __forceinline__ float keyToF(unsigned k) {
  return (k & 0x80000000u) ? __uint_as_float(k & 0x7fffffffu)
                           : -__uint_as_float(~k);
}

// ---------------------------------------------------------------------------
// prep: convert W2 (128x64) and W3 (384x128) to bf16, row-major (plain).
// ---------------------------------------------------------------------------
__global__ void prep_kernel(const float* __restrict__ W2, const float* __restrict__ W3,
                            short* __restrict__ w2bf, short* __restrict__ w3bf) {
  int i = blockIdx.x * 256 + threadIdx.x;
  if (i < C2_*C1_) w2bf[i] = (short)f2bf(W2[i]);
  int j = i - C2_*C1_;
  if (j >= 0 && j < C3_*C2_) w3bf[j] = (short)f2bf(W3[j]);
}

// ---------------------------------------------------------------------------
// FPS: one block (1024 threads) per batch. 16 points/thread in registers.
// launch_bounds(1024,4): VGPR cap 128 -> no scratch spill. One barrier/step
// (double-buffered winner slots); final 16-winner reduce is lane-parallel.
// Distance replicates XLA contraction: fma(dz,dz,fma(dy,dy,dx*dx)).
// ---------------------------------------------------------------------------
__global__ __launch_bounds__(1024, 4) void fps_kernel(const float* __restrict__ x,
        float* __restrict__ centers, float* __restrict__ outCent) {
  int b = blockIdx.x;
  int t = threadIdx.x;
  const float* xb = x + (size_t)b * N_ * 3;
  float px[16], py[16], pz[16], dist[16];
#pragma unroll
  for (int j = 0; j < 16; ++j) {
    int n = j * 1024 + t;
    px[j] = xb[n*3+0]; py[j] = xb[n*3+1]; pz[j] = xb[n*3+2];
    dist[j] = 1e10f;
  }
  __shared__ float wd[2][16];
  __shared__ int   wi[2][16];
  float cx = xb[0], cy = xb[1], cz = xb[2];
  int lane = t & 63, wv = t >> 6;
  for (int s = 0; s < S_; ++s) {
    if (t == 0) {
      int task = b * S_ + s;
      centers[task*3+0] = cx; centers[task*3+1] = cy; centers[task*3+2] = cz;
      outCent[task*3+0] = cx; outCent[task*3+1] = cy; outCent[task*3+2] = cz;
    }
    float bd = -1.0f; int bn = 0;
#pragma unroll
    for (int j = 0; j < 16; ++j) {
      float dx = px[j]-cx, dy = py[j]-cy, dz = pz[j]-cz;
      float d = __builtin_fmaf(dz, dz, __builtin_fmaf(dy, dy, dx*dx));
      float dm = fminf(dist[j], d);
      dist[j] = dm;
      int n = j*1024 + t;
      if (dm > bd) { bd = dm; bn = n; }
    }
#pragma unroll
    for (int m = 1; m < 64; m <<= 1) {
      float od = __shfl_xor(bd, m, 64); int on = __shfl_xor(bn, m, 64);
      if (od > bd || (od == bd && on < bn)) { bd = od; bn = on; }
    }
    int buf = s & 1;
    if (lane == 0) { wd[buf][wv] = bd; wi[buf][wv] = bn; }
    __syncthreads();
    float vd = wd[buf][lane & 15];
    int   vi = wi[buf][lane & 15];
#pragma unroll
    for (int m = 1; m < 16; m <<= 1) {
      float od = __shfl_xor(vd, m, 64); int oi = __shfl_xor(vi, m, 64);
      if (od > vd || (od == vd && oi < vi)) { vd = od; vi = oi; }
    }
    int gn = vi;
    cx = xb[gn*3+0]; cy = xb[gn*3+1]; cz = xb[gn*3+2];
  }
}

// ---------------------------------------------------------------------------
// query_ball v8: BARRIER-FREE per-wave selection (R8's structure, the 155us
// best, minus its spill). 1024 threads (16 waves), key[16]/thread (~40 VGPR
// under the 64-cap of launch_bounds(1024,8) -> 2 blocks/CU, 32 waves/CU).
// Each wave owns 1024 points, selects its exact top-32 by (key,idx) with
// ZERO block barriers: 64-sample threshold -> <=4 secant refines (2/3-power
// model) into window [32,64] -> ballot-compact -> 64-wide wave rank.
// Wave-local radix-bisection fallback (early-stop + exact-T tie path).
// Global top-32 = one barrier + 512-way tournament = reference top_k.
// ---------------------------------------------------------------------------
__global__ __launch_bounds__(1024, 8) void qb_kernel(const float* __restrict__ x,
        const float* __restrict__ centers, float* __restrict__ patches) {
  int t = threadIdx.x;
  int lane = t & 63, wv = t >> 6;    // 16 waves
  int task = blockIdx.x;
  int b = task >> 6;
  const float* xb = x + (size_t)b * N_ * 3;
  float cx = centers[task*3+0], cy = centers[task*3+1], cz = centers[task*3+2];
  float A = __builtin_fmaf(cz, cz, __builtin_fmaf(cy, cy, cx*cx));

  __shared__ unsigned long long wbuf[16][64];   // 8 KB per-wave candidates
  __shared__ unsigned long long tour[512];      // 4 KB wave top-32s
  __shared__ int winIdx[32];
  __shared__ int sortedIdx[32];

  unsigned key[16];
  unsigned kmin = 0xffffffffu;
  int base = wv * 1024;
#pragma unroll
  for (int j = 0; j < 16; ++j) {
    int n = base + j*64 + lane;
    float qx = xb[n*3+0], qy = xb[n*3+1], qz = xb[n*3+2];
    float Bn = __builtin_fmaf(qz, qz, __builtin_fmaf(qy, qy, qx*qx));
    float dt = __builtin_fmaf(cz, qz, __builtin_fmaf(cy, qy, cx*qx));
    float d  = __builtin_fmaf(-2.0f, dt, A + Bn);
    unsigned k = fToKey(d);
    key[j] = k;
    kmin = min(kmin, k);
  }
  unsigned ksam = key[0];              // 64 samples of this wave's 1024
#pragma unroll
  for (int m = 1; m < 64; m <<= 1) {
    kmin = min(kmin, (unsigned)__shfl_xor((int)kmin, m, 64));
    ksam = min(ksam, (unsigned)__shfl_xor((int)ksam, m, 64));
  }

  // wave-uniform count of {key < T} (no barriers)
  auto wcount = [&](unsigned T) -> int {
    int cc = 0;
#pragma unroll
    for (int j = 0; j < 16; ++j) cc += (key[j] < T) ? 1 : 0;
#pragma unroll
    for (int m = 1; m < 64; m <<= 1) cc += __shfl_xor(cc, m, 64);
    return cc;
  };

  unsigned Tcur = ksam;
  int c = wcount(Tcur);
  float dmin = keyToF(kmin);
  for (int iter = 0; iter < 4 && !(c >= 32 && c <= 64); ++iter) {
    float dcur = keyToF(Tcur);
    if (!(dcur > dmin)) break;
    float f = 48.0f / fmaxf((float)c, 2.0f);
    float ratio = exp2f(0.66666667f * log2f(f));   // count ~ (d-dmin)^1.5
    float dnew = dmin + (dcur - dmin) * ratio;
    unsigned Tn = fToKey(dnew);
    if (Tn == Tcur) break;
    Tcur = Tn;
    c = wcount(Tcur);
  }

  int cw = 0;
  bool ok = (c >= 32 && c <= 64);
  if (!ok) {
    // wave-local radix bisection (AND/OR bit-skip, early-stop [32,64])
    unsigned a = 0xffffffffu, o = 0u;
#pragma unroll
    for (int j = 0; j < 16; ++j) { a &= key[j]; o |= key[j]; }
#pragma unroll
    for (int m = 1; m < 64; m <<= 1) {
      a &= (unsigned)__shfl_xor((int)a, m, 64);
      o |= (unsigned)__shfl_xor((int)o, m, 64);
    }
    unsigned diff = a ^ o, result = 0u;
    bool early = false;
    for (int bit = 31; bit >= 0; --bit) {
      unsigned msk = 1u << bit;
      if (!(diff & msk)) { result |= (a & msk); continue; }
      unsigned tryv = result | msk;
      int cc = wcount(tryv);
      if (cc >= 32 && cc <= 64) { early = true; Tcur = tryv; break; }
      if (cc < 32) result = tryv;
    }
    if (early) {
      ok = true;
    } else {
      // exact boundary key Tx: strict-less (<32) + index-ordered tie fill
      unsigned Tx = result;
      int bpos = 0;
#pragma unroll
      for (int j = 0; j < 16; ++j) {
        bool p = key[j] < Tx;
        unsigned long long mk = __ballot(p);
        if (p) {
          int pos = bpos + (int)__popcll(mk & ((1ull << lane) - 1ull));
          wbuf[wv][pos] = ((unsigned long long)key[j] << 32) | (unsigned)(base + j*64 + lane);
        }
        bpos += (int)__popcll(mk);
      }
      int cl = bpos;                 // < 32
      int need = 32 - cl;
      int picked = -1;
      for (int r = 0; r < need; ++r) {
        int candn = 0x7fffffff;
#pragma unroll
        for (int j = 0; j < 16; ++j) {
          int n = base + j*64 + lane;
          if (key[j] == Tx && n > picked && n < candn) candn = n;
        }
#pragma unroll
        for (int m = 1; m < 64; m <<= 1) candn = min(candn, __shfl_xor(candn, m, 64));
        if (lane == 0)
          wbuf[wv][cl + r] = ((unsigned long long)Tx << 32) | (unsigned)candn;
        picked = candn;
      }
      cw = 32;
    }
  }
  if (ok) {
    int bpos = 0;
#pragma unroll
    for (int j = 0; j < 16; ++j) {
      bool p = key[j] < Tcur;
      unsigned long long mk = __ballot(p);
      if (p) {
        int pos = bpos + (int)__popcll(mk & ((1ull << lane) - 1ull));
        wbuf[wv][pos] = ((unsigned long long)key[j] << 32) | (unsigned)(base + j*64 + lane);
      }
      bpos += (int)__popcll(mk);
    }
    cw = bpos;                       // in [32,64]
  }

  // wave rank: top-32 of cw (<=64) candidates -> tour[wv*32 + r]
  {
    unsigned long long me = (lane < cw) ? wbuf[wv][lane] : ~0ull;
    int rk = 0;
    for (int jj = 0; jj < cw; ++jj) rk += (wbuf[wv][jj] < me) ? 1 : 0;
    if (lane < cw && rk < 32) tour[wv*32 + rk] = me;
  }
  __syncthreads();   // the ONE block barrier before the tournament

  // tournament: exact top-32 of the 512 wave winners
  if (t < 512) {
    unsigned long long me = tour[t];
    int rk = 0;
    for (int jj = 0; jj < 512; ++jj) rk += (tour[jj] < me) ? 1 : 0;
    if (rk < 32) winIdx[rk] = (int)(me & 0xffffffffu);
  }
  __syncthreads();
  if (t < 32) {
    int v = winIdx[t];
    int slot = 0;
#pragma unroll
    for (int j = 0; j < 32; ++j) slot += (winIdx[j] < v) ? 1 : 0;
    sortedIdx[slot] = v;
  }
  __syncthreads();
  if (t < 32) {
    int n = sortedIdx[t];
    float qx = xb[n*3+0], qy = xb[n*3+1], qz = xb[n*3+2];
    size_t row = (size_t)task * K_ + t;
    patches[row*3+0] = qx - cx;
    patches[row*3+1] = qy - cy;
    patches[row*3+2] = qz - cz;
  }
}

// ---------------------------------------------------------------------------
// mom: 9 moments of patches (Sx,Sy,Sz,Sxx,Syy,Szz,Sxy,Sxz,Syz) -> mom[48][9]
// ---------------------------------------------------------------------------
__global__ __launch_bounds__(256) void mom_kernel(const float* __restrict__ patches,
        float* __restrict__ mom) {
  int t = threadIdx.x;
  float s[9] = {0,0,0,0,0,0,0,0,0};
  for (int r = blockIdx.x*256 + t; r < R_; r += MOMB_*256) {
    const float* p = patches + (size_t)r*3;
    float x0 = p[0], y0 = p[1], z0 = p[2];
    s[0] += x0; s[1] += y0; s[2] += z0;
    s[3] += x0*x0; s[4] += y0*y0; s[5] += z0*z0;
    s[6] += x0*y0; s[7] += x0*z0; s[8] += y0*z0;
  }
  __shared__ float red[4][9];
  int lane = t & 63, wv = t >> 6;
#pragma unroll
  for (int k = 0; k < 9; ++k) {
    float v = s[k];
#pragma unroll
    for (int m = 1; m < 64; m <<= 1) v += __shfl_xor(v, m, 64);
    if (lane == 0) red[wv][k] = v;
  }
  __syncthreads();
  if (t < 9) mom[blockIdx.x*9 + t] = red[0][t] + red[1][t] + red[2][t] + red[3][t];
}

// ---------------------------------------------------------------------------
// finalize1: layer-1 BN scale/shift from the 9 moments (double combine).
// ---------------------------------------------------------------------------
__global__ void finalize1_kernel(const float* __restrict__ mom,
        const float* __restrict__ W1, const float* __restrict__ b1,
        const float* __restrict__ g, const float* __restrict__ be,
        float* __restrict__ scale, float* __restrict__ shift) {
  int o = threadIdx.x;
  __shared__ double M[9];
  if (o < 9) {
    double ss = 0.0;
    for (int i = 0; i < MOMB_; ++i) ss += (double)mom[i*9 + o];
    M[o] = ss;
  }
  __syncthreads();
  if (o >= C1_) return;
  double w0 = W1[o*3], w1 = W1[o*3+1], w2 = W1[o*3+2], bb = b1[o];
  double wSp = w0*M[0] + w1*M[1] + w2*M[2];
  double s1 = wSp + (double)R_*bb;
  double s2 = w0*w0*M[3] + w1*w1*M[4] + w2*w2*M[5]
            + 2.0*(w0*w1*M[6] + w0*w2*M[7] + w1*w2*M[8])
            + 2.0*bb*wSp + (double)R_*bb*bb;
  float m   = (float)(s1 / (double)R_);
  float eh2 = (float)(s2 / (double)R_);
  float v = eh2 - m*m;
  float rs = rsqrtf(v + BN_EPS_);
  float sc = g[o] * rs;
  scale[o] = sc;
  shift[o] = be[o] - m*sc;
}

// ---------------------------------------------------------------------------
// finalize: deterministic sum of partials -> scale/shift (BN affine form).
// If bias != nullptr, folds a pre-BN linear bias into shift.
// ---------------------------------------------------------------------------
__global__ void finalize_kernel(const float* __restrict__ part, int nblk, int nch,
        const float* __restrict__ g, const float* __restrict__ be,
        const float* __restrict__ bias,
        float* __restrict__ scale, float* __restrict__ shift) {
  int o = threadIdx.x;
  if (o >= nch) return;
  double s1 = 0.0, s2 = 0.0;
  for (int i = 0; i < nblk; ++i) {
    s1 += (double)part[i*nch*2 + o*2 + 0];
    s2 += (double)part[i*nch*2 + o*2 + 1];
  }
  float m   = (float)(s1 / (double)R_);
  float eh2 = (float)(s2 / (double)R_);
  float v = eh2 - m*m;
  float rs = rsqrtf(v + BN_EPS_);
  float sc = g[o] * rs;
  scale[o] = sc;
  float sh = be[o] - m*sc;
  if (bias) sh += bias[o]*sc;
  shift[o] = sh;
}

// ---------------------------------------------------------------------------
// stats2: 512 blocks x 256 rows (2 tiles of 128): recompute a1 tile (LDS),
// h2 = a1@W2^T + b2 (fp32), per-channel sum/sumsq.
// ---------------------------------------------------------------------------
__global__ __launch_bounds__(256) void stats2_kernel(const float* __restrict__ patches,
        const float* __restrict__ W1, const float* __restrict__ b1,
        const float* __restrict__ sc1, const float* __restrict__ sh1,
        const float* __restrict__ W2, const float* __restrict__ b2,
        float* __restrict__ part) {
  __shared__ float a1L[128][68];
  __shared__ float red[2][128][2];
  int t = threadIdx.x;
  float4 wreg[16];
  const float4* w2r = (const float4*)(W2 + (t & 127)*64);
#pragma unroll
  for (int c = 0; c < 16; ++c) wreg[c] = w2r[c];
  float bb = b2[t & 127];
  float s1 = 0.f, s2 = 0.f;
  int rg = t >> 7;
  for (int tile = 0; tile < 2; ++tile) {
    int r0 = blockIdx.x * 256 + tile * 128;
    {
      int r = t & 127, oh = t >> 7;
      const float* p = patches + (size_t)(r0 + r) * 3;
      float p0 = p[0], p1 = p[1], p2 = p[2];
#pragma unroll
      for (int j = 0; j < 32; ++j) {
        int o = oh*32 + j;
        float h = p0*W1[o*3] + p1*W1[o*3+1] + p2*W1[o*3+2] + b1[o];
        a1L[r][o] = fmaxf(h*sc1[o] + sh1[o], 0.f);
      }
    }
    __syncthreads();
    for (int i = 0; i < 64; ++i) {
      int r = rg*64 + i;
      float acc = bb;
      const float4* a4 = (const float4*)(&a1L[r][0]);
#pragma unroll
      for (int c = 0; c < 16; ++c) {
        float4 a = a4[c];
        acc += a.x*wreg[c].x; acc += a.y*wreg[c].y;
        acc += a.z*wreg[c].z; acc += a.w*wreg[c].w;
      }
      s1 += acc; s2 += acc*acc;
    }
    __syncthreads();
  }
  red[rg][t & 127][0] = s1; red[rg][t & 127][1] = s2;
  __syncthreads();
  if (t < 128) {
    part[blockIdx.x*256 + t*2 + 0] = red[0][t][0] + red[1][t][0];
    part[blockIdx.x*256 + t*2 + 1] = red[0][t][1] + red[1][t][1];
  }
}

// ---------------------------------------------------------------------------
// embed (MFMA): 4 tasks/block (M=128 rows), 256 threads (4 waves, 1 task/wave).
// ---------------------------------------------------------------------------
__global__ __launch_bounds__(256) void embed_kernel(
        const float* __restrict__ patches,
        const float* __restrict__ W1, const float* __restrict__ b1,
        const float* __restrict__ sc1, const float* __restrict__ sh1,
        const short* __restrict__ w2bf, const float* __restrict__ sc2,
        const float* __restrict__ sh2f,
        const short* __restrict__ w3bf, const float* __restrict__ b3,
        float* __restrict__ out) {
  __shared__ char lds[49152];   // a1L @0 (16KB), a2L @16384 (32KB)
  int t = threadIdx.x;
  int l = t & 63, w = t >> 6;
  int lo = l & 15, hi = l >> 4;

  // ---- P1 ----
  {
    int row = t >> 1, half = t & 1;
    const float* p = patches + ((size_t)blockIdx.x*128 + row)*3;
    float p0 = p[0], p1 = p[1], p2 = p[2];
    int swz = (row & 7) << 4;
    char* dst = lds + row*128;
#pragma unroll
    for (int g = 0; g < 4; ++g) {
      unsigned short pk[8];
#pragma unroll
      for (int j = 0; j < 8; ++j) {
        int o = half*32 + g*8 + j;
        float h = p0*W1[o*3] + p1*W1[o*3+1] + p2*W1[o*3+2] + b1[o];
        pk[j] = f2bf(fmaxf(h*sc1[o] + sh1[o], 0.f));
      }
      int4 v;
      v.x = pk[0] | (pk[1]<<16); v.y = pk[2] | (pk[3]<<16);
      v.z = pk[4] | (pk[5]<<16); v.w = pk[6] | (pk[7]<<16);
      *(int4*)(dst + (((half*64 + g*16)) ^ swz)) = v;
    }
  }
  __syncthreads();

  // ---- P2 ----
  {
    bf16x8 af[2][2];
#pragma unroll
    for (int mt = 0; mt < 2; ++mt) {
      int row = w*32 + mt*16 + lo;
#pragma unroll
      for (int ks = 0; ks < 2; ++ks)
        af[mt][ks] = *(const bf16x8*)(lds + row*128 + ((ks*64 + hi*16) ^ ((row&7)<<4)));
    }
#pragma unroll
    for (int nt = 0; nt < 8; ++nt) {
      f32x4 acc0 = {0.f,0.f,0.f,0.f}, acc1 = {0.f,0.f,0.f,0.f};
      int n = nt*16 + lo;
#pragma unroll
      for (int ks = 0; ks < 2; ++ks) {
        bf16x8 bfv = *(const bf16x8*)(w2bf + n*64 + ks*32 + hi*8);
        acc0 = __builtin_amdgcn_mfma_f32_16x16x32_bf16(af[0][ks], bfv, acc0, 0, 0, 0);
        acc1 = __builtin_amdgcn_mfma_f32_16x16x32_bf16(af[1][ks], bfv, acc1, 0, 0, 0);
      }
      float sc = sc2[n], sh = sh2f[n];
#pragma unroll
      for (int mt = 0; mt < 2; ++mt) {
        f32x4 c = mt ? acc1 : acc0;
#pragma unroll
        for (int r = 0; r < 4; ++r) {
          int row = w*32 + mt*16 + hi*4 + r;
          unsigned short v = f2bf(fmaxf(c[r]*sc + sh, 0.f));
          *(short*)(lds + 16384 + row*256 + ((n*2) ^ ((row&7)<<4))) = (short)v;
        }
      }
    }
  }
  __syncthreads();

  // ---- P3 ----
  {
    bf16x8 af[2][4];
#pragma unroll
    for (int mt = 0; mt < 2; ++mt) {
      int row = w*32 + mt*16 + lo;
#pragma unroll
      for (int ks = 0; ks < 4; ++ks)
        af[mt][ks] = *(const bf16x8*)(lds + 16384 + row*256 + ((ks*64 + hi*16) ^ ((row&7)<<4)));
    }
    size_t gtask = (size_t)blockIdx.x*4 + w;
#pragma unroll 4
    for (int nt = 0; nt < 24; ++nt) {
      f32x4 acc0 = {0.f,0.f,0.f,0.f}, acc1 = {0.f,0.f,0.f,0.f};
      int e = nt*16 + lo;
#pragma unroll
      for (int ks = 0; ks < 4; ++ks) {
        bf16x8 bfv = *(const bf16x8*)(w3bf + e*128 + ks*32 + hi*8);
        acc0 = __builtin_amdgcn_mfma_f32_16x16x32_bf16(af[0][ks], bfv, acc0, 0, 0, 0);
        acc1 = __builtin_amdgcn_mfma_f32_16x16x32_bf16(af[1][ks], bfv, acc1, 0, 0, 0);
      }
      float m0 = fmaxf(fmaxf(acc0[0], acc0[1]), fmaxf(acc0[2], acc0[3]));
      float m1 = fmaxf(fmaxf(acc1[0], acc1[1]), fmaxf(acc1[2], acc1[3]));
      float m = fmaxf(m0, m1);
      m = fmaxf(m, __shfl_xor(m, 16, 64));
      m = fmaxf(m, __shfl_xor(m, 32, 64));
      if (l < 16) out[gtask*C3_ + e] = m + b3[e];
    }
  }
}

// ---------------------------------------------------------------------------
extern "C" void kernel_launch(void* const* d_in, const int* in_sizes, int n_in,
                              void* d_out, int out_size, void* d_ws, size_t ws_size,
                              hipStream_t stream) {
  (void)in_sizes; (void)n_in; (void)out_size; (void)ws_size;
  const float* x   = (const float*)d_in[0];
  const float* W1  = (const float*)d_in[1];
  const float* b1  = (const float*)d_in[2];
  const float* g1  = (const float*)d_in[3];
  const float* be1 = (const float*)d_in[4];
  const float* W2  = (const float*)d_in[5];
  const float* b2  = (const float*)d_in[6];
  const float* g2  = (const float*)d_in[7];
  const float* be2 = (const float*)d_in[8];
  const float* W3  = (const float*)d_in[9];
  const float* b3  = (const float*)d_in[10];
  float* out = (float*)d_out;
  float* ws  = (float*)d_ws;

  float* patches = ws + PATCH_OFF;
  float* centers = ws + CENT_OFF;
  float* mom1    = ws + P1_OFF;
  float* sc1     = ws + SC1_OFF; float* sh1 = sc1 + C1_;
  float* part2   = ws + P2_OFF;
  float* sc2     = ws + SC2_OFF; float* sh2 = sc2 + C2_;
  short* w2bf    = (short*)(ws + W2BF_OFF);
  short* w3bf    = (short*)(ws + W3BF_OFF);
  float* outCent = out + (size_t)B_*S_*C3_;

  prep_kernel<<<dim3((C2_*C1_ + C3_*C2_)/256), dim3(256), 0, stream>>>(W2, W3, w2bf, w3bf);
  fps_kernel<<<dim3(B_), dim3(1024), 0, stream>>>(x, centers, outCent);
  qb_kernel<<<dim3(4096), dim3(1024), 0, stream>>>(x, centers, patches);
  mom_kernel<<<dim3(MOMB_), dim3(256), 0, stream>>>(patches, mom1);
  finalize1_kernel<<<dim3(1), dim3(64), 0, stream>>>(mom1, W1, b1, g1, be1, sc1, sh1);
  stats2_kernel<<<dim3(NB2_), dim3(256), 0, stream>>>(patches, W1, b1, sc1, sh1, W2, b2, part2);
  finalize_kernel<<<dim3(1), dim3(128), 0, stream>>>(part2, NB2_, C2_, g2, be2, b2, sc2, sh2);
  embed_kernel<<<dim3(1024), dim3(256), 0, stream>>>(patches, W1, b1, sc1, sh1,
                                                     w2bf, sc2, sh2, w3bf, b3, out);
}

// Round 13
// 661.707 us; speedup vs baseline: 1.0651x; 1.0079x over previous
//
#include <hip/hip_runtime.h>
#include <hip/hip_bf16.h>

// Problem constants
#define B_  64
#define N_  16384
#define S_  64      // NUM_PATCHES
#define K_  32      // PATCH_POINTS
#define C1_ 64
#define C2_ 128
#define C3_ 384
#define R_  (B_*S_*K_)   // 131072 rows
#define BN_EPS_ 1e-5f

// ws layout (float offsets)
#define PATCH_OFF 0
#define CENT_OFF  (R_*3)                      // 393216
#define P1_OFF    (CENT_OFF + B_*S_*3)        // 405504 (mom: 4096*9 floats)
#define SC1_OFF   (P1_OFF + 65536)            // 471040
#define NB2_ 512
#define P2_OFF    (SC1_OFF + 2*C1_)           // 471168
#define SC2_OFF   (P2_OFF + NB2_*C2_*2)       // 602240
#define W2BF_OFF  (SC2_OFF + 2*C2_)           // 602496 (floats; holds 8192 shorts)
#define W3BF_OFF  (W2BF_OFF + 4096)           // 606592 (floats; holds 49152 shorts)
// end = 631168 floats (~2.52 MB)

typedef short bf16x8 __attribute__((ext_vector_type(8)));
typedef float f32x4  __attribute__((ext_vector_type(4)));

static __device__ __forceinline__ unsigned short f2bf(float f) {
  unsigned u = __float_as_uint(f);
  unsigned r = (u + 0x7fffu + ((u >> 16) & 1u)) >> 16;   // RNE
  return (unsigned short)r;
}

static __device__ __forceinline__ unsigned fToKey(float d) {
  unsigned u = __float_as_uint(d);
  return (u & 0x80000000u) ? ~u : (u | 0x80000000u);
}
static __device__ __forceinline__ float keyToF(unsigned k) {
  return (k & 0x80000000u) ? __uint_as_float(k & 0x7fffffffu)
                           : -__uint_as_float(~k);
}

// ---------------------------------------------------------------------------
// prep: convert W2 (128x64) and W3 (384x128) to bf16, row-major (plain).
// ---------------------------------------------------------------------------
__global__ void prep_kernel(const float* __restrict__ W2, const float* __restrict__ W3,
                            short* __restrict__ w2bf, short* __restrict__ w3bf) {
  int i = blockIdx.x * 256 + threadIdx.x;
  if (i < C2_*C1_) w2bf[i] = (short)f2bf(W2[i]);
  int j = i - C2_*C1_;
  if (j >= 0 && j < C3_*C2_) w3bf[j] = (short)f2bf(W3[j]);
}

// ---------------------------------------------------------------------------
// FPS: one block (1024 threads) per batch. 16 points/thread in registers.
// launch_bounds(1024,4): VGPR cap 128 -> no scratch spill. One barrier/step
// (double-buffered winner slots); final 16-winner reduce is lane-parallel.
// Distance replicates XLA contraction: fma(dz,dz,fma(dy,dy,dx*dx)).
// ---------------------------------------------------------------------------
__global__ __launch_bounds__(1024, 4) void fps_kernel(const float* __restrict__ x,
        float* __restrict__ centers, float* __restrict__ outCent) {
  int b = blockIdx.x;
  int t = threadIdx.x;
  const float* xb = x + (size_t)b * N_ * 3;
  float px[16], py[16], pz[16], dist[16];
#pragma unroll
  for (int j = 0; j < 16; ++j) {
    int n = j * 1024 + t;
    px[j] = xb[n*3+0]; py[j] = xb[n*3+1]; pz[j] = xb[n*3+2];
    dist[j] = 1e10f;
  }
  __shared__ float wd[2][16];
  __shared__ int   wi[2][16];
  float cx = xb[0], cy = xb[1], cz = xb[2];
  int lane = t & 63, wv = t >> 6;
  for (int s = 0; s < S_; ++s) {
    if (t == 0) {
      int task = b * S_ + s;
      centers[task*3+0] = cx; centers[task*3+1] = cy; centers[task*3+2] = cz;
      outCent[task*3+0] = cx; outCent[task*3+1] = cy; outCent[task*3+2] = cz;
    }
    float bd = -1.0f; int bn = 0;
#pragma unroll
    for (int j = 0; j < 16; ++j) {
      float dx = px[j]-cx, dy = py[j]-cy, dz = pz[j]-cz;
      float d = __builtin_fmaf(dz, dz, __builtin_fmaf(dy, dy, dx*dx));
      float dm = fminf(dist[j], d);
      dist[j] = dm;
      int n = j*1024 + t;
      if (dm > bd) { bd = dm; bn = n; }
    }
#pragma unroll
    for (int m = 1; m < 64; m <<= 1) {
      float od = __shfl_xor(bd, m, 64); int on = __shfl_xor(bn, m, 64);
      if (od > bd || (od == bd && on < bn)) { bd = od; bn = on; }
    }
    int buf = s & 1;
    if (lane == 0) { wd[buf][wv] = bd; wi[buf][wv] = bn; }
    __syncthreads();
    float vd = wd[buf][lane & 15];
    int   vi = wi[buf][lane & 15];
#pragma unroll
    for (int m = 1; m < 16; m <<= 1) {
      float od = __shfl_xor(vd, m, 64); int oi = __shfl_xor(vi, m, 64);
      if (od > vd || (od == vd && oi < vi)) { vd = od; vi = oi; }
    }
    int gn = vi;
    cx = xb[gn*3+0]; cy = xb[gn*3+1]; cz = xb[gn*3+2];
  }
}

// ---------------------------------------------------------------------------
// query_ball v9: barrier-free per-wave selection (R12 structure) + pruned
// binary-search tournament. 1024 threads (16 waves), key[16]/thread, no
// spill at the 64-VGPR cap (launch_bounds(1024,8)). Per-wave exact top-32
// (sampled threshold + secant + radix fallback) -> sorted 32-segments in
// tour[]; T* early-out + 16x6-step lower_bound gives global ranks (exact
// reference top_k). Tail: lanes 0-31 emit the task's 9 patch moments.
// ---------------------------------------------------------------------------
__global__ __launch_bounds__(1024, 8) void qb_kernel(const float* __restrict__ x,
        const float* __restrict__ centers, float* __restrict__ patches,
        float* __restrict__ mom) {
  int t = threadIdx.x;
  int lane = t & 63, wv = t >> 6;    // 16 waves
  int task = blockIdx.x;
  int b = task >> 6;
  const float* xb = x + (size_t)b * N_ * 3;
  float cx = centers[task*3+0], cy = centers[task*3+1], cz = centers[task*3+2];
  float A = __builtin_fmaf(cz, cz, __builtin_fmaf(cy, cy, cx*cx));

  __shared__ unsigned long long wbuf[16][64];   // 8 KB per-wave candidates
  __shared__ unsigned long long tour[512];      // 4 KB wave top-32s (sorted segs)
  __shared__ int winIdx[32];
  __shared__ int sortedIdx[32];

  unsigned key[16];
  unsigned kmin = 0xffffffffu;
  int base = wv * 1024;
#pragma unroll
  for (int j = 0; j < 16; ++j) {
    int n = base + j*64 + lane;
    float qx = xb[n*3+0], qy = xb[n*3+1], qz = xb[n*3+2];
    float Bn = __builtin_fmaf(qz, qz, __builtin_fmaf(qy, qy, qx*qx));
    float dt = __builtin_fmaf(cz, qz, __builtin_fmaf(cy, qy, cx*qx));
    float d  = __builtin_fmaf(-2.0f, dt, A + Bn);
    unsigned k = fToKey(d);
    key[j] = k;
    kmin = min(kmin, k);
  }
  unsigned ksam = key[0];              // 64 samples of this wave's 1024
#pragma unroll
  for (int m = 1; m < 64; m <<= 1) {
    kmin = min(kmin, (unsigned)__shfl_xor((int)kmin, m, 64));
    ksam = min(ksam, (unsigned)__shfl_xor((int)ksam, m, 64));
  }

  // wave-uniform count of {key < T} (no barriers)
  auto wcount = [&](unsigned T) -> int {
    int cc = 0;
#pragma unroll
    for (int j = 0; j < 16; ++j) cc += (key[j] < T) ? 1 : 0;
#pragma unroll
    for (int m = 1; m < 64; m <<= 1) cc += __shfl_xor(cc, m, 64);
    return cc;
  };

  unsigned Tcur = ksam;
  int c = wcount(Tcur);
  float dmin = keyToF(kmin);
  for (int iter = 0; iter < 4 && !(c >= 32 && c <= 64); ++iter) {
    float dcur = keyToF(Tcur);
    if (!(dcur > dmin)) break;
    float f = 48.0f / fmaxf((float)c, 2.0f);
    float ratio = exp2f(0.66666667f * log2f(f));   // count ~ (d-dmin)^1.5
    float dnew = dmin + (dcur - dmin) * ratio;
    unsigned Tn = fToKey(dnew);
    if (Tn == Tcur) break;
    Tcur = Tn;
    c = wcount(Tcur);
  }

  int cw = 0;
  bool ok = (c >= 32 && c <= 64);
  if (!ok) {
    // wave-local radix bisection (AND/OR bit-skip, early-stop [32,64])
    unsigned a = 0xffffffffu, o = 0u;
#pragma unroll
    for (int j = 0; j < 16; ++j) { a &= key[j]; o |= key[j]; }
#pragma unroll
    for (int m = 1; m < 64; m <<= 1) {
      a &= (unsigned)__shfl_xor((int)a, m, 64);
      o |= (unsigned)__shfl_xor((int)o, m, 64);
    }
    unsigned diff = a ^ o, result = 0u;
    bool early = false;
    for (int bit = 31; bit >= 0; --bit) {
      unsigned msk = 1u << bit;
      if (!(diff & msk)) { result |= (a & msk); continue; }
      unsigned tryv = result | msk;
      int cc = wcount(tryv);
      if (cc >= 32 && cc <= 64) { early = true; Tcur = tryv; break; }
      if (cc < 32) result = tryv;
    }
    if (early) {
      ok = true;
    } else {
      // exact boundary key Tx: strict-less (<32) + index-ordered tie fill
      unsigned Tx = result;
      int bpos = 0;
#pragma unroll
      for (int j = 0; j < 16; ++j) {
        bool p = key[j] < Tx;
        unsigned long long mk = __ballot(p);
        if (p) {
          int pos = bpos + (int)__popcll(mk & ((1ull << lane) - 1ull));
          wbuf[wv][pos] = ((unsigned long long)key[j] << 32) | (unsigned)(base + j*64 + lane);
        }
        bpos += (int)__popcll(mk);
      }
      int cl = bpos;                 // < 32
      int need = 32 - cl;
      int picked = -1;
      for (int r = 0; r < need; ++r) {
        int candn = 0x7fffffff;
#pragma unroll
        for (int j = 0; j < 16; ++j) {
          int n = base + j*64 + lane;
          if (key[j] == Tx && n > picked && n < candn) candn = n;
        }
#pragma unroll
        for (int m = 1; m < 64; m <<= 1) candn = min(candn, __shfl_xor(candn, m, 64));
        if (lane == 0)
          wbuf[wv][cl + r] = ((unsigned long long)Tx << 32) | (unsigned)candn;
        picked = candn;
      }
      cw = 32;
    }
  }
  if (ok) {
    int bpos = 0;
#pragma unroll
    for (int j = 0; j < 16; ++j) {
      bool p = key[j] < Tcur;
      unsigned long long mk = __ballot(p);
      if (p) {
        int pos = bpos + (int)__popcll(mk & ((1ull << lane) - 1ull));
        wbuf[wv][pos] = ((unsigned long long)key[j] << 32) | (unsigned)(base + j*64 + lane);
      }
      bpos += (int)__popcll(mk);
    }
    cw = bpos;                       // in [32,64]
  }

  // wave rank: top-32 of cw (<=64) candidates -> tour[wv*32 + r] (sorted seg)
  {
    unsigned long long me = (lane < cw) ? wbuf[wv][lane] : ~0ull;
    int rk = 0;
    for (int jj = 0; jj < cw; ++jj) rk += (wbuf[wv][jj] < me) ? 1 : 0;
    if (lane < cw && rk < 32) tour[wv*32 + rk] = me;
  }
  __syncthreads();   // the ONE block barrier before the tournament

  // pruned tournament: T* = min over waves of segment max; candidates > T*
  // have >=32 elements below them (min-wave's full segment) -> early out.
  // Active candidates get exact global rank via 16 sorted lower_bounds.
  if (t < 512) {
    unsigned long long me = tour[t];
    unsigned long long Tstar = tour[31];
#pragma unroll
    for (int w = 1; w < 16; ++w) {
      unsigned long long v = tour[w*32 + 31];
      if (v < Tstar) Tstar = v;
    }
    if (me <= Tstar) {
      int rk = 0;
#pragma unroll
      for (int w = 0; w < 16; ++w) {
        const unsigned long long* seg = &tour[w*32];
        int pos = 0;
#pragma unroll
        for (int s = 32; s > 0; s >>= 1) {
          if (pos + s <= 32 && seg[pos + s - 1] < me) pos += s;
        }
        rk += pos;
      }
      if (rk < 32) winIdx[rk] = (int)(me & 0xffffffffu);
    }
  }
  __syncthreads();
  if (t < 32) {
    int v = winIdx[t];
    int slot = 0;
#pragma unroll
    for (int j = 0; j < 32; ++j) slot += (winIdx[j] < v) ? 1 : 0;
    sortedIdx[slot] = v;
  }
  __syncthreads();
  if (t < 32) {
    int n = sortedIdx[t];
    float qx = xb[n*3+0] - cx, qy = xb[n*3+1] - cy, qz = xb[n*3+2] - cz;
    size_t row = (size_t)task * K_ + t;
    patches[row*3+0] = qx;
    patches[row*3+1] = qy;
    patches[row*3+2] = qz;
    // per-task 9 moments (lanes 0..31 of wave 0; 5-step shfl reduce)
    float mv[9];
    mv[0]=qx; mv[1]=qy; mv[2]=qz;
    mv[3]=qx*qx; mv[4]=qy*qy; mv[5]=qz*qz;
    mv[6]=qx*qy; mv[7]=qx*qz; mv[8]=qy*qz;
#pragma unroll
    for (int k = 0; k < 9; ++k) {
      float v = mv[k];
#pragma unroll
      for (int m = 1; m < 32; m <<= 1) v += __shfl_xor(v, m, 64);
      if (t == 0) mom[(size_t)task*9 + k] = v;
    }
  }
}

// ---------------------------------------------------------------------------
// finalize1: layer-1 BN scale/shift from 4096 per-task 9-moment partials.
// 576 threads = 64 groups x 9 moments; deterministic two-stage reduction.
// ---------------------------------------------------------------------------
__global__ __launch_bounds__(576) void finalize1_kernel(const float* __restrict__ mom,
        const float* __restrict__ W1, const float* __restrict__ b1,
        const float* __restrict__ g, const float* __restrict__ be,
        float* __restrict__ scale, float* __restrict__ shift) {
  int t = threadIdx.x;
  __shared__ float part[64][9];
  if (t < 576) {
    int gp = t / 9, k = t % 9;
    float s = 0.f;
    for (int i = gp; i < 4096; i += 64) s += mom[(size_t)i*9 + k];
    part[gp][k] = s;
  }
  __syncthreads();
  __shared__ double M[9];
  if (t < 9) {
    double ss = 0.0;
    for (int g2 = 0; g2 < 64; ++g2) ss += (double)part[g2][t];
    M[t] = ss;
  }
  __syncthreads();
  int o = t;
  if (o >= C1_) return;
  double w0 = W1[o*3], w1 = W1[o*3+1], w2 = W1[o*3+2], bb = b1[o];
  double wSp = w0*M[0] + w1*M[1] + w2*M[2];
  double s1 = wSp + (double)R_*bb;
  double s2 = w0*w0*M[3] + w1*w1*M[4] + w2*w2*M[5]
            + 2.0*(w0*w1*M[6] + w0*w2*M[7] + w1*w2*M[8])
            + 2.0*bb*wSp + (double)R_*bb*bb;
  float m   = (float)(s1 / (double)R_);
  float eh2 = (float)(s2 / (double)R_);
  float v = eh2 - m*m;
  float rs = rsqrtf(v + BN_EPS_);
  float sc = g[o] * rs;
  scale[o] = sc;
  shift[o] = be[o] - m*sc;
}

// ---------------------------------------------------------------------------
// finalize: deterministic sum of partials -> scale/shift (BN affine form).
// If bias != nullptr, folds a pre-BN linear bias into shift.
// ---------------------------------------------------------------------------
__global__ void finalize_kernel(const float* __restrict__ part, int nblk, int nch,
        const float* __restrict__ g, const float* __restrict__ be,
        const float* __restrict__ bias,
        float* __restrict__ scale, float* __restrict__ shift) {
  int o = threadIdx.x;
  if (o >= nch) return;
  double s1 = 0.0, s2 = 0.0;
  for (int i = 0; i < nblk; ++i) {
    s1 += (double)part[i*nch*2 + o*2 + 0];
    s2 += (double)part[i*nch*2 + o*2 + 1];
  }
  float m   = (float)(s1 / (double)R_);
  float eh2 = (float)(s2 / (double)R_);
  float v = eh2 - m*m;
  float rs = rsqrtf(v + BN_EPS_);
  float sc = g[o] * rs;
  scale[o] = sc;
  float sh = be[o] - m*sc;
  if (bias) sh += bias[o]*sc;
  shift[o] = sh;
}

// ---------------------------------------------------------------------------
// stats2: 512 blocks x 256 rows (2 tiles of 128): recompute a1 tile (LDS),
// h2 = a1@W2^T + b2 (fp32), per-channel sum/sumsq.
// ---------------------------------------------------------------------------
__global__ __launch_bounds__(256) void stats2_kernel(const float* __restrict__ patches,
        const float* __restrict__ W1, const float* __restrict__ b1,
        const float* __restrict__ sc1, const float* __restrict__ sh1,
        const float* __restrict__ W2, const float* __restrict__ b2,
        float* __restrict__ part) {
  __shared__ float a1L[128][68];
  __shared__ float red[2][128][2];
  int t = threadIdx.x;
  float4 wreg[16];
  const float4* w2r = (const float4*)(W2 + (t & 127)*64);
#pragma unroll
  for (int c = 0; c < 16; ++c) wreg[c] = w2r[c];
  float bb = b2[t & 127];
  float s1 = 0.f, s2 = 0.f;
  int rg = t >> 7;
  for (int tile = 0; tile < 2; ++tile) {
    int r0 = blockIdx.x * 256 + tile * 128;
    {
      int r = t & 127, oh = t >> 7;
      const float* p = patches + (size_t)(r0 + r) * 3;
      float p0 = p[0], p1 = p[1], p2 = p[2];
#pragma unroll
      for (int j = 0; j < 32; ++j) {
        int o = oh*32 + j;
        float h = p0*W1[o*3] + p1*W1[o*3+1] + p2*W1[o*3+2] + b1[o];
        a1L[r][o] = fmaxf(h*sc1[o] + sh1[o], 0.f);
      }
    }
    __syncthreads();
    for (int i = 0; i < 64; ++i) {
      int r = rg*64 + i;
      float acc = bb;
      const float4* a4 = (const float4*)(&a1L[r][0]);
#pragma unroll
      for (int c = 0; c < 16; ++c) {
        float4 a = a4[c];
        acc += a.x*wreg[c].x; acc += a.y*wreg[c].y;
        acc += a.z*wreg[c].z; acc += a.w*wreg[c].w;
      }
      s1 += acc; s2 += acc*acc;
    }
    __syncthreads();
  }
  red[rg][t & 127][0] = s1; red[rg][t & 127][1] = s2;
  __syncthreads();
  if (t < 128) {
    part[blockIdx.x*256 + t*2 + 0] = red[0][t][0] + red[1][t][0];
    part[blockIdx.x*256 + t*2 + 1] = red[0][t][1] + red[1][t][1];
  }
}

// ---------------------------------------------------------------------------
// embed (MFMA): 4 tasks/block (M=128 rows), 256 threads (4 waves, 1 task/wave).
// ---------------------------------------------------------------------------
__global__ __launch_bounds__(256) void embed_kernel(
        const float* __restrict__ patches,
        const float* __restrict__ W1, const float* __restrict__ b1,
        const float* __restrict__ sc1, const float* __restrict__ sh1,
        const short* __restrict__ w2bf, const float* __restrict__ sc2,
        const float* __restrict__ sh2f,
        const short* __restrict__ w3bf, const float* __restrict__ b3,
        float* __restrict__ out) {
  __shared__ char lds[49152];   // a1L @0 (16KB), a2L @16384 (32KB)
  int t = threadIdx.x;
  int l = t & 63, w = t >> 6;
  int lo = l & 15, hi = l >> 4;

  // ---- P1 ----
  {
    int row = t >> 1, half = t & 1;
    const float* p = patches + ((size_t)blockIdx.x*128 + row)*3;
    float p0 = p[0], p1 = p[1], p2 = p[2];
    int swz = (row & 7) << 4;
    char* dst = lds + row*128;
#pragma unroll
    for (int g = 0; g < 4; ++g) {
      unsigned short pk[8];
#pragma unroll
      for (int j = 0; j < 8; ++j) {
        int o = half*32 + g*8 + j;
        float h = p0*W1[o*3] + p1*W1[o*3+1] + p2*W1[o*3+2] + b1[o];
        pk[j] = f2bf(fmaxf(h*sc1[o] + sh1[o], 0.f));
      }
      int4 v;
      v.x = pk[0] | (pk[1]<<16); v.y = pk[2] | (pk[3]<<16);
      v.z = pk[4] | (pk[5]<<16); v.w = pk[6] | (pk[7]<<16);
      *(int4*)(dst + (((half*64 + g*16)) ^ swz)) = v;
    }
  }
  __syncthreads();

  // ---- P2 ----
  {
    bf16x8 af[2][2];
#pragma unroll
    for (int mt = 0; mt < 2; ++mt) {
      int row = w*32 + mt*16 + lo;
#pragma unroll
      for (int ks = 0; ks < 2; ++ks)
        af[mt][ks] = *(const bf16x8*)(lds + row*128 + ((ks*64 + hi*16) ^ ((row&7)<<4)));
    }
#pragma unroll
    for (int nt = 0; nt < 8; ++nt) {
      f32x4 acc0 = {0.f,0.f,0.f,0.f}, acc1 = {0.f,0.f,0.f,0.f};
      int n = nt*16 + lo;
#pragma unroll
      for (int ks = 0; ks < 2; ++ks) {
        bf16x8 bfv = *(const bf16x8*)(w2bf + n*64 + ks*32 + hi*8);
        acc0 = __builtin_amdgcn_mfma_f32_16x16x32_bf16(af[0][ks], bfv, acc0, 0, 0, 0);
        acc1 = __builtin_amdgcn_mfma_f32_16x16x32_bf16(af[1][ks], bfv, acc1, 0, 0, 0);
      }
      float sc = sc2[n], sh = sh2f[n];
#pragma unroll
      for (int mt = 0; mt < 2; ++mt) {
        f32x4 c = mt ? acc1 : acc0;
#pragma unroll
        for (int r = 0; r < 4; ++r) {
          int row = w*32 + mt*16 + hi*4 + r;
          unsigned short v = f2bf(fmaxf(c[r]*sc + sh, 0.f));
          *(short*)(lds + 16384 + row*256 + ((n*2) ^ ((row&7)<<4))) = (short)v;
        }
      }
    }
  }
  __syncthreads();

  // ---- P3 ----
  {
    bf16x8 af[2][4];
#pragma unroll
    for (int mt = 0; mt < 2; ++mt) {
      int row = w*32 + mt*16 + lo;
#pragma unroll
      for (int ks = 0; ks < 4; ++ks)
        af[mt][ks] = *(const bf16x8*)(lds + 16384 + row*256 + ((ks*64 + hi*16) ^ ((row&7)<<4)));
    }
    size_t gtask = (size_t)blockIdx.x*4 + w;
#pragma unroll 4
    for (int nt = 0; nt < 24; ++nt) {
      f32x4 acc0 = {0.f,0.f,0.f,0.f}, acc1 = {0.f,0.f,0.f,0.f};
      int e = nt*16 + lo;
#pragma unroll
      for (int ks = 0; ks < 4; ++ks) {
        bf16x8 bfv = *(const bf16x8*)(w3bf + e*128 + ks*32 + hi*8);
        acc0 = __builtin_amdgcn_mfma_f32_16x16x32_bf16(af[0][ks], bfv, acc0, 0, 0, 0);
        acc1 = __builtin_amdgcn_mfma_f32_16x16x32_bf16(af[1][ks], bfv, acc1, 0, 0, 0);
      }
      float m0 = fmaxf(fmaxf(acc0[0], acc0[1]), fmaxf(acc0[2], acc0[3]));
      float m1 = fmaxf(fmaxf(acc1[0], acc1[1]), fmaxf(acc1[2], acc1[3]));
      float m = fmaxf(m0, m1);
      m = fmaxf(m, __shfl_xor(m, 16, 64));
      m = fmaxf(m, __shfl_xor(m, 32, 64));
      if (l < 16) out[gtask*C3_ + e] = m + b3[e];
    }
  }
}

// ---------------------------------------------------------------------------
extern "C" void kernel_launch(void* const* d_in, const int* in_sizes, int n_in,
                              void* d_out, int out_size, void* d_ws, size_t ws_size,
                              hipStream_t stream) {
  (void)in_sizes; (void)n_in; (void)out_size; (void)ws_size;
  const float* x   = (const float*)d_in[0];
  const float* W1  = (const float*)d_in[1];
  const float* b1  = (const float*)d_in[2];
  const float* g1  = (const float*)d_in[3];
  const float* be1 = (const float*)d_in[4];
  const float* W2  = (const float*)d_in[5];
  const float* b2  = (const float*)d_in[6];
  const float* g2  = (const float*)d_in[7];
  const float* be2 = (const float*)d_in[8];
  const float* W3  = (const float*)d_in[9];
  const float* b3  = (const float*)d_in[10];
  float* out = (float*)d_out;
  float* ws  = (float*)d_ws;

  float* patches = ws + PATCH_OFF;
  float* centers = ws + CENT_OFF;
  float* mom1    = ws + P1_OFF;
  float* sc1     = ws + SC1_OFF; float* sh1 = sc1 + C1_;
  float* part2   = ws + P2_OFF;
  float* sc2     = ws + SC2_OFF; float* sh2 = sc2 + C2_;
  short* w2bf    = (short*)(ws + W2BF_OFF);
  short* w3bf    = (short*)(ws + W3BF_OFF);
  float* outCent = out + (size_t)B_*S_*C3_;

  prep_kernel<<<dim3((C2_*C1_ + C3_*C2_)/256), dim3(256), 0, stream>>>(W2, W3, w2bf, w3bf);
  fps_kernel<<<dim3(B_), dim3(1024), 0, stream>>>(x, centers, outCent);
  qb_kernel<<<dim3(4096), dim3(1024), 0, stream>>>(x, centers, patches, mom1);
  finalize1_kernel<<<dim3(1), dim3(576), 0, stream>>>(mom1, W1, b1, g1, be1, sc1, sh1);
  stats2_kernel<<<dim3(NB2_), dim3(256), 0, stream>>>(patches, W1, b1, sc1, sh1, W2, b2, part2);
  finalize_kernel<<<dim3(1), dim3(128), 0, stream>>>(part2, NB2_, C2_, g2, be2, b2, sc2, sh2);
  embed_kernel<<<dim3(1024), dim3(256), 0, stream>>>(patches, W1, b1, sc1, sh1,
                                                     w2bf, sc2, sh2, w3bf, b3, out);
}